// Round 2
// baseline (2578.012 us; speedup 1.0000x reference)
//
#include <hip/hip_runtime.h>

// SchNet fused kernel, fp32 baseline.
// One block per batch element. All intermediates in LDS.
// 64 atoms, 64 features, 64 rbf. Pairs padded to 64x64 with j==i masked.

#define NATOMS 64
#define NFEA   64

__device__ __forceinline__ float tanh_fast(float x) {
    float ax = fabsf(x);
    float e  = __expf(2.0f * ax);
    float r  = 1.0f - 2.0f / (e + 1.0f);   // tanh(|x|), stable for large ax (inf -> 1)
    return copysignf(r, x);
}

// 64x64x64 GEMM: Out[r][c] = act( sum_k As[k][r] * Ws[k][c] + bias[c] )
// As is K-major (transposed A), Ws is natural (k rows, c cols), both LDS.
// ACT: 0 = none, 1 = tanh
// SMODE: 0 = natural store Out[r*64+c], 1 = transposed store Out[c*64+r],
//        2 = transposed accumulate Out[c*64+r] += val
template <int ACT, int SMODE>
__device__ __forceinline__ void gemm64(const float* As, const float* Ws,
                                       const float* __restrict__ bias,
                                       float* Out, int tid) {
    const int r0 = (tid & 15) << 2;
    const int c0 = (tid >> 4) << 2;
    float acc[4][4];
#pragma unroll
    for (int i = 0; i < 4; ++i)
#pragma unroll
        for (int j = 0; j < 4; ++j) acc[i][j] = 0.0f;

#pragma unroll 8
    for (int k = 0; k < 64; ++k) {
        const float4 a = *(const float4*)(As + (k << 6) + r0);
        const float4 w = *(const float4*)(Ws + (k << 6) + c0);
        acc[0][0] = fmaf(a.x, w.x, acc[0][0]);
        acc[0][1] = fmaf(a.x, w.y, acc[0][1]);
        acc[0][2] = fmaf(a.x, w.z, acc[0][2]);
        acc[0][3] = fmaf(a.x, w.w, acc[0][3]);
        acc[1][0] = fmaf(a.y, w.x, acc[1][0]);
        acc[1][1] = fmaf(a.y, w.y, acc[1][1]);
        acc[1][2] = fmaf(a.y, w.z, acc[1][2]);
        acc[1][3] = fmaf(a.y, w.w, acc[1][3]);
        acc[2][0] = fmaf(a.z, w.x, acc[2][0]);
        acc[2][1] = fmaf(a.z, w.y, acc[2][1]);
        acc[2][2] = fmaf(a.z, w.z, acc[2][2]);
        acc[2][3] = fmaf(a.z, w.w, acc[2][3]);
        acc[3][0] = fmaf(a.w, w.x, acc[3][0]);
        acc[3][1] = fmaf(a.w, w.y, acc[3][1]);
        acc[3][2] = fmaf(a.w, w.z, acc[3][2]);
        acc[3][3] = fmaf(a.w, w.w, acc[3][3]);
    }

    const float4 bvec = *(const float4*)(bias + c0);
    float bb[4] = {bvec.x, bvec.y, bvec.z, bvec.w};
    float v[4][4];
#pragma unroll
    for (int rr = 0; rr < 4; ++rr)
#pragma unroll
        for (int cc = 0; cc < 4; ++cc) {
            float x = acc[rr][cc] + bb[cc];
            v[rr][cc] = (ACT == 1) ? tanh_fast(x) : x;
        }

    if (SMODE == 0) {
#pragma unroll
        for (int rr = 0; rr < 4; ++rr) {
            *(float4*)(Out + (r0 + rr) * 64 + c0) =
                make_float4(v[rr][0], v[rr][1], v[rr][2], v[rr][3]);
        }
    } else {
#pragma unroll
        for (int cc = 0; cc < 4; ++cc) {
            float4 col = make_float4(v[0][cc], v[1][cc], v[2][cc], v[3][cc]);
            float4* p = (float4*)(Out + (c0 + cc) * 64 + r0);
            if (SMODE == 2) {
                float4 o = *p;
                col.x += o.x; col.y += o.y; col.z += o.z; col.w += o.w;
            }
            *p = col;
        }
    }
}

__global__ __launch_bounds__(256) void schnet_kernel(
    const float* __restrict__ r,    const float* __restrict__ v1,
    const float* __restrict__ v2,   const float* __restrict__ cent,
    const float* __restrict__ Wx,   const float* __restrict__ bx,
    const float* __restrict__ Wf1,  const float* __restrict__ bf1,
    const float* __restrict__ Wf2,  const float* __restrict__ bf2,
    const float* __restrict__ Wv1,  const float* __restrict__ bv1,
    const float* __restrict__ Wv2,  const float* __restrict__ bv2,
    const float* __restrict__ W1,   const float* __restrict__ b1,
    const float* __restrict__ W2,   const float* __restrict__ b2,
    float* __restrict__ out) {
    __shared__ __align__(16) float sD[4096];    // d[i][j]
    __shared__ __align__(16) float sXT[4096];   // X transposed: sXT[k][a]
    __shared__ __align__(16) float sXl[4096];   // Xl[a][c] natural
    __shared__ __align__(16) float sVT[4096];   // v transposed: sVT[c][i]
    __shared__ __align__(16) float sA[4096];    // rbf_T / h2
    __shared__ __align__(16) float sB[4096];    // h1_T / u_T
    __shared__ __align__(16) float sW0[4096];   // Wx / Wv1 / W1
    __shared__ __align__(16) float sWa[4096];   // Wf1 / Wv2
    __shared__ __align__(16) float sWb[4096];   // Wf2
    __shared__ __align__(16) float sPos[256];
    __shared__ float sCent[64];
    __shared__ float sPart[256];
    __shared__ float sRed[64];

    const int b = blockIdx.x;
    const int tid = threadIdx.x;

    if (tid < 192) sPos[tid] = r[b * 192 + tid];
    if (tid < 64) sCent[tid] = cent[tid];
    __syncthreads();

    // pairwise distances (full 64x64, diagonal = 0, masked later)
    for (int idx = tid; idx < 4096; idx += 256) {
        int i = idx >> 6, j = idx & 63;
        float dx = sPos[i * 3 + 0] - sPos[j * 3 + 0];
        float dy = sPos[i * 3 + 1] - sPos[j * 3 + 1];
        float dz = sPos[i * 3 + 2] - sPos[j * 3 + 2];
        sD[idx] = sqrtf(dx * dx + dy * dy + dz * dz);
    }
    // X init, stored transposed: atoms 0,1 -> v1, rest -> v2
    for (int idx = tid; idx < 4096; idx += 256) {
        int a = idx & 63, c = idx >> 6;
        sXT[c * 64 + a] = (a < 2) ? v1[c] : v2[c];
    }
    __syncthreads();

    for (int t = 0; t < 3; ++t) {
        // stage weights for this interaction
        {
            const float4* gWx  = (const float4*)(Wx  + t * 4096);
            const float4* gWf1 = (const float4*)(Wf1 + t * 4096);
            const float4* gWf2 = (const float4*)(Wf2 + t * 4096);
            for (int idx = tid; idx < 1024; idx += 256) {
                ((float4*)sW0)[idx] = gWx[idx];
                ((float4*)sWa)[idx] = gWf1[idx];
                ((float4*)sWb)[idx] = gWf2[idx];
            }
        }
        __syncthreads();

        // Xl = X @ Wx + bx  (natural layout, no activation)
        gemm64<0, 0>(sXT, sW0, bx + t * 64, sXl, tid);
        __syncthreads();

        for (int i = 0; i < 64; ++i) {
            // rbf for atom i's 64 (padded) neighbors, stored transposed [k][j]
            {
                int j = tid & 63;
                int k0 = (tid >> 6) << 4;
                float dij = sD[i * 64 + j];
#pragma unroll
                for (int kk = 0; kk < 16; ++kk) {
                    int k = k0 + kk;
                    float x = dij - sCent[k];
                    sA[(k << 6) + j] = __expf(-10.0f * x * x);
                }
            }
            __syncthreads();
            gemm64<1, 1>(sA, sWa, bf1 + t * 64, sB, tid);   // h1_T = tanh(rbf@Wf1+b)
            __syncthreads();
            gemm64<1, 0>(sB, sWb, bf2 + t * 64, sA, tid);   // h2 = tanh(h1@Wf2+b)
            __syncthreads();
            // cfconv scatter-sum: v[i][c] = sum_{j != i} h2[j][c] * Xl[j][c]
            {
                int c = tid & 63;
                int w = tid >> 6;
                int j0 = w << 4;
                float s = 0.0f;
#pragma unroll
                for (int jj = 0; jj < 16; ++jj) {
                    int j = j0 + jj;
                    float hv = sA[j * 64 + c] * sXl[j * 64 + c];
                    s += (j == i) ? 0.0f : hv;
                }
                sPart[tid] = s;
            }
            __syncthreads();
            if (tid < 64) {
                sVT[tid * 64 + i] = sPart[tid] + sPart[64 + tid] +
                                    sPart[128 + tid] + sPart[192 + tid];
            }
            __syncthreads();
        }

        // stage Wv1 -> sW0, Wv2 -> sWa
        {
            const float4* gWv1 = (const float4*)(Wv1 + t * 4096);
            const float4* gWv2 = (const float4*)(Wv2 + t * 4096);
            for (int idx = tid; idx < 1024; idx += 256) {
                ((float4*)sW0)[idx] = gWv1[idx];
                ((float4*)sWa)[idx] = gWv2[idx];
            }
        }
        __syncthreads();
        gemm64<1, 1>(sVT, sW0, bv1 + t * 64, sB, tid);      // u_T = tanh(v@Wv1+b)
        __syncthreads();
        gemm64<0, 2>(sB, sWa, bv2 + t * 64, sXT, tid);      // X += u@Wv2+b
        __syncthreads();
    }

    // head: Y = tanh(X@W1+b1) (64x32), then per-atom dot W2 + b2, sum atoms
    for (int idx = tid; idx < 512; idx += 256)
        ((float4*)sW0)[idx] = ((const float4*)W1)[idx];
    __syncthreads();
    {
        int c = tid & 31;
        int a0 = (tid >> 5) << 3;
        float bc = b1[c];
#pragma unroll
        for (int aa = 0; aa < 8; ++aa) {
            int a = a0 + aa;
            float s = bc;
#pragma unroll 8
            for (int k = 0; k < 64; ++k) s = fmaf(sXT[(k << 6) + a], sW0[(k << 5) + c], s);
            sA[a * 32 + c] = tanh_fast(s);
        }
    }
    __syncthreads();
    if (tid < 64) {
        float s = b2[0];
#pragma unroll
        for (int k = 0; k < 32; ++k) s = fmaf(sA[tid * 32 + k], W2[k], s);
        sRed[tid] = s;
    }
    __syncthreads();
    if (tid == 0) {
        float s = 0.0f;
        for (int a = 0; a < 64; ++a) s += sRed[a];
        out[b] = s;
    }
}

extern "C" void kernel_launch(void* const* d_in, const int* in_sizes, int n_in,
                              void* d_out, int out_size, void* d_ws, size_t ws_size,
                              hipStream_t stream) {
    const float* r    = (const float*)d_in[0];
    const float* v1   = (const float*)d_in[1];
    const float* v2   = (const float*)d_in[2];
    const float* cent = (const float*)d_in[3];
    const float* Wx   = (const float*)d_in[4];
    const float* bx   = (const float*)d_in[5];
    const float* Wf1  = (const float*)d_in[6];
    const float* bf1  = (const float*)d_in[7];
    const float* Wf2  = (const float*)d_in[8];
    const float* bf2  = (const float*)d_in[9];
    const float* Wv1  = (const float*)d_in[10];
    const float* bv1  = (const float*)d_in[11];
    const float* Wv2  = (const float*)d_in[12];
    const float* bv2  = (const float*)d_in[13];
    const float* W1   = (const float*)d_in[14];
    const float* b1   = (const float*)d_in[15];
    const float* W2   = (const float*)d_in[16];
    const float* b2   = (const float*)d_in[17];

    schnet_kernel<<<512, 256, 0, stream>>>(r, v1, v2, cent, Wx, bx, Wf1, bf1,
                                           Wf2, bf2, Wv1, bv1, Wv2, bv2, W1, b1,
                                           W2, b2, (float*)d_out);
}

// Round 5
// 942.960 us; speedup vs baseline: 2.7340x; 2.7340x over previous
//
#include <hip/hip_runtime.h>

// SchNet fused, bf16-MFMA with hi/lo split operands (fp32-class accuracy).
// One block per batch element, 256 threads (4 waves), 2 blocks/CU (76.4KB LDS).
// All GEMM operands are (hi,lo) bf16 pairs; 3-term MFMA hi*hi+hi*lo+lo*hi.
// Weights: prep_weights writes per-(mat,wave,lane) A-fragments (hi+lo) to d_ws;
// waves load them global->VGPR (L2-resident), no LDS staging.
// Activations in LDS: hi plane + lo plane (+8192B), XOR-swizzled rows.
// Xl kept fp32 in LDS (cfconv fully fp32). X master fp32 in registers;
// X_lo plane materialized into bB between layers for the Xl/head GEMMs.

typedef __attribute__((ext_vector_type(8))) __bf16 bf16x8;
typedef __attribute__((ext_vector_type(4))) __bf16 bf16x4;
typedef __attribute__((ext_vector_type(4))) float  f32x4;

__device__ __forceinline__ int swz(int row, int byteoff) {
    return row * 128 + (byteoff ^ ((row & 7) << 4));
}
__device__ __forceinline__ int swz32(int row, int byteoff) {  // f32 rows, 256B
    return row * 256 + (byteoff ^ ((row & 7) << 5));
}

__device__ __forceinline__ float tanh_fast(float x) {
    float t = exp2f(2.88539008f * x);
    return fmaf(-2.0f, __builtin_amdgcn_rcpf(t + 1.0f), 1.0f);
}

struct AFrag { bf16x8 a0h, a1h, a0l, a1l; };

__device__ __forceinline__ AFrag load_afrag(const char* wsW, int mat, int wv, int lane) {
    const char* p = wsW + mat * 16384 + wv * 2048 + lane * 32;
    AFrag f;
    f.a0h = *(const bf16x8*)(p);
    f.a1h = *(const bf16x8*)(p + 16);
    f.a0l = *(const bf16x8*)(p + 8192);
    f.a1l = *(const bf16x8*)(p + 8192 + 16);
    return f;
}

// 3-term split GEMM: D[m][n] = A*B, A from frag regs, B hi/lo planes in LDS.
// EPI 0: f32 store to OutF (swz32, +bias, no act)  [Xl]
// EPI 1: bf16 hi/lo store to OutHi/OutHi+8192 (+bias, tanh)  [h1,h2,u]
// EPI 2: raw acc -> ret  [Wv2]
template <int EPI>
__device__ __forceinline__ void gemm64s(const AFrag& A, const char* Bhi, const char* Blo,
                                        const float* __restrict__ bias,
                                        char* OutHi, float* OutF,
                                        int lane, int wv, f32x4* ret) {
    const int l15 = lane & 15, q = lane >> 4;
    f32x4 acc[4];
#pragma unroll
    for (int nt = 0; nt < 4; ++nt) {
        const int n = 16 * nt + l15;
        const bf16x8 b0h = *(const bf16x8*)(Bhi + swz(n, 16 * q));
        const bf16x8 b1h = *(const bf16x8*)(Bhi + swz(n, 64 + 16 * q));
        const bf16x8 b0l = *(const bf16x8*)(Blo + swz(n, 16 * q));
        const bf16x8 b1l = *(const bf16x8*)(Blo + swz(n, 64 + 16 * q));
        f32x4 c = {0.f, 0.f, 0.f, 0.f};
        c = __builtin_amdgcn_mfma_f32_16x16x32_bf16(A.a0h, b0h, c, 0, 0, 0);
        c = __builtin_amdgcn_mfma_f32_16x16x32_bf16(A.a1h, b1h, c, 0, 0, 0);
        c = __builtin_amdgcn_mfma_f32_16x16x32_bf16(A.a0h, b0l, c, 0, 0, 0);
        c = __builtin_amdgcn_mfma_f32_16x16x32_bf16(A.a1h, b1l, c, 0, 0, 0);
        c = __builtin_amdgcn_mfma_f32_16x16x32_bf16(A.a0l, b0h, c, 0, 0, 0);
        c = __builtin_amdgcn_mfma_f32_16x16x32_bf16(A.a1l, b1h, c, 0, 0, 0);
        acc[nt] = c;
    }
    if (EPI == 2) {
#pragma unroll
        for (int nt = 0; nt < 4; ++nt) ret[nt] = acc[nt];
        return;
    }
    const f32x4 bv = *(const f32x4*)(bias + 16 * wv + 4 * q);
#pragma unroll
    for (int nt = 0; nt < 4; ++nt) {
        const int n = 16 * nt + l15;
        if (EPI == 0) {
            f32x4 o;
#pragma unroll
            for (int r = 0; r < 4; ++r) o[r] = acc[nt][r] + bv[r];
            *(f32x4*)((char*)OutF + swz32(n, 64 * wv + 16 * q)) = o;
        } else {
            bf16x4 oh, ol;
#pragma unroll
            for (int r = 0; r < 4; ++r) {
                float v = tanh_fast(acc[nt][r] + bv[r]);
                __bf16 h = (__bf16)v;
                oh[r] = h;
                ol[r] = (__bf16)(v - (float)h);
            }
            const int off = swz(n, 32 * wv + 8 * q);
            *(bf16x4*)(OutHi + off) = oh;
            *(bf16x4*)(OutHi + 8192 + off) = ol;
        }
    }
}

// Emit A-fragments (hi+lo) for all 16 matrices into ws.
// mat m<15: t=m/5, s=m%5 {Wx,Wf1,Wf2,Wv1,Wv2}; m=15: W1 (64x32, rows>=32 pad 0).
// src is [k][n] (n=f_out contiguous); A-frag row m_row = f_out, k = f_in.
__global__ void prep_weights(const float* __restrict__ Wx, const float* __restrict__ Wf1,
                             const float* __restrict__ Wf2, const float* __restrict__ Wv1,
                             const float* __restrict__ Wv2, const float* __restrict__ W1,
                             char* __restrict__ ws) {
    const int m = blockIdx.x;
    const int tid = threadIdx.x;
    const int wv = tid >> 6, lane = tid & 63;
    const int l15 = lane & 15, q = lane >> 4;
    const int m_row = 16 * wv + l15;
    const float* src;
    int wcols;
    if (m < 15) {
        const int t = m / 5, s = m % 5;
        src = (s == 0 ? Wx : s == 1 ? Wf1 : s == 2 ? Wf2 : s == 3 ? Wv1 : Wv2) + t * 4096;
        wcols = 64;
    } else {
        src = W1;
        wcols = 32;
    }
    char* base = ws + m * 16384 + wv * 2048 + lane * 32;
#pragma unroll
    for (int kc = 0; kc < 2; ++kc) {
        bf16x8 hi, lo;
#pragma unroll
        for (int e = 0; e < 8; ++e) {
            const int k = 32 * kc + 8 * q + e;
            float val = (m_row < wcols) ? src[k * wcols + m_row] : 0.0f;
            __bf16 h = (__bf16)val;
            hi[e] = h;
            lo[e] = (__bf16)(val - (float)h);
        }
        *(bf16x8*)(base + kc * 16) = hi;
        *(bf16x8*)(base + 8192 + kc * 16) = lo;
    }
}

__global__ __launch_bounds__(256, 2) void schnet_mfma(
    const float* __restrict__ r,   const float* __restrict__ v1g,
    const float* __restrict__ v2g, const float* __restrict__ cent,
    const float* __restrict__ bx,  const float* __restrict__ bf1,
    const float* __restrict__ bf2, const float* __restrict__ bv1,
    const float* __restrict__ bv2, const float* __restrict__ b1,
    const float* __restrict__ W2,  const float* __restrict__ b2,
    const char* __restrict__ wsW,  float* __restrict__ out) {
    extern __shared__ char smem[];
    char* bX  = smem;                         // 8192  X hi [atom][f]
    float* bXl = (float*)(smem + 8192);       // 16384 Xl f32 [atom][f] swz32
    char* bV  = smem + 24576;                 // 16384 v hi/lo [atom][f]
    char* bA  = smem + 40960;                 // 16384 rbf/h2 hi/lo [j][k]
    char* bB  = smem + 57344;                 // 16384 h1/u hi/lo; X_lo in [0:8192)
    float* sPos   = (float*)(smem + 73728);   // [3][64] planar
    float* sCent  = (float*)(smem + 74496);
    float* sPartF = (float*)(smem + 74752);   // [4][64] f32
    float* sRed   = (float*)(smem + 75776);   // [2][64] f32
    float* sW2v   = (float*)(smem + 76288);   // 128B  -> total 76416

    const int tid = threadIdx.x;
    const int lane = tid & 63, wv = tid >> 6;
    const int l15 = lane & 15, q = lane >> 4;
    const int b = blockIdx.x;

    if (tid < 192) sPos[(tid % 3) * 64 + tid / 3] = r[b * 192 + tid];
    if (tid < 64) sCent[tid] = cent[tid];
    if (tid < 32) sW2v[tid] = W2[tid];

    // persistent filter-weight fragments (updated per layer)
    AFrag fWf1 = load_afrag(wsW, 1, wv, lane);
    AFrag fWf2 = load_afrag(wsW, 2, wv, lane);

    // X master init (fp32 regs) + hi to bX, lo to bB[0:8192)
    f32x4 master[4];
    {
        const f32x4 a1v = *(const f32x4*)(v1g + 16 * wv + 4 * q);
        const f32x4 a2v = *(const f32x4*)(v2g + 16 * wv + 4 * q);
#pragma unroll
        for (int nt = 0; nt < 4; ++nt) {
            const bool isv1 = (nt == 0) && (l15 < 2);
            bf16x4 oh, ol;
#pragma unroll
            for (int rr = 0; rr < 4; ++rr) {
                master[nt][rr] = isv1 ? a1v[rr] : a2v[rr];
                __bf16 h = (__bf16)master[nt][rr];
                oh[rr] = h;
                ol[rr] = (__bf16)(master[nt][rr] - (float)h);
            }
            const int off = swz(16 * nt + l15, 32 * wv + 8 * q);
            *(bf16x4*)(bX + off) = oh;
            *(bf16x4*)(bB + off) = ol;
        }
    }
    __syncthreads();

    for (int t = 0; t < 3; ++t) {
        // Xl = X@Wx + bx -> fp32 (B: hi=bX, lo=bB X_lo plane)
        {
            AFrag fWx = load_afrag(wsW, t * 5 + 0, wv, lane);
            gemm64s<0>(fWx, bX, bB, bx + t * 64, nullptr, bXl, lane, wv, nullptr);
        }
        __syncthreads();   // Xl visible; bB free for h1

        for (int i = 0; i < 64; ++i) {
            {   // rbf hi/lo for pair row j=lane, k-chunk per wave -> bA
                const int j = lane;
                const float dx = sPos[j] - sPos[i];
                const float dy = sPos[64 + j] - sPos[64 + i];
                const float dz = sPos[128 + j] - sPos[128 + i];
                const float d = sqrtf(dx * dx + dy * dy + dz * dz);
                bf16x8 h0, h1, l0, l1;
#pragma unroll
                for (int e = 0; e < 8; ++e) {
                    float x0 = d - sCent[wv * 16 + e];
                    float x1 = d - sCent[wv * 16 + 8 + e];
                    float v0 = exp2f(-14.4269504f * x0 * x0);
                    float v1 = exp2f(-14.4269504f * x1 * x1);
                    __bf16 hh0 = (__bf16)v0, hh1 = (__bf16)v1;
                    h0[e] = hh0; l0[e] = (__bf16)(v0 - (float)hh0);
                    h1[e] = hh1; l1[e] = (__bf16)(v1 - (float)hh1);
                }
                const int o0 = swz(j, 32 * wv), o1 = swz(j, 32 * wv + 16);
                *(bf16x8*)(bA + o0) = h0;
                *(bf16x8*)(bA + o1) = h1;
                *(bf16x8*)(bA + 8192 + o0) = l0;
                *(bf16x8*)(bA + 8192 + o1) = l1;
            }
            __syncthreads();
            gemm64s<1>(fWf1, bA, bA + 8192, bf1 + t * 64, bB, nullptr, lane, wv, nullptr);
            __syncthreads();
            gemm64s<1>(fWf2, bB, bB + 8192, bf2 + t * 64, bA, nullptr, lane, wv, nullptr);
            __syncthreads();
            {   // cfconv (fp32): p[f] = sum_{j in wave's 16, j!=i} h2[j][f]*Xl[j][f]
                const int f = lane;
                float p = 0.f;
#pragma unroll
                for (int jj = 0; jj < 16; ++jj) {
                    const int j = 16 * wv + jj;
                    if (j == i) continue;
                    const int off = swz(j, 2 * f);
                    float h2v = (float)*(const __bf16*)(bA + off) +
                                (float)*(const __bf16*)(bA + 8192 + off);
                    float xl = *(const float*)((char*)bXl + swz32(j, 4 * f));
                    p = fmaf(h2v, xl, p);
                }
                sPartF[tid] = p;
            }
            __syncthreads();
            if (tid < 64) {
                float s = sPartF[tid] + sPartF[64 + tid] + sPartF[128 + tid] + sPartF[192 + tid];
                __bf16 h = (__bf16)s;
                const int off = swz(i, 2 * tid);
                *(__bf16*)(bV + off) = h;
                *(__bf16*)(bV + 8192 + off) = (__bf16)(s - (float)h);
            }
            // next rbf write to bA is after this iteration's barrier chain; safe.
        }
        __syncthreads();   // bV complete
        {
            AFrag fWv1 = load_afrag(wsW, t * 5 + 3, wv, lane);
            gemm64s<1>(fWv1, bV, bV + 8192, bv1 + t * 64, bB, nullptr, lane, wv, nullptr);
        }
        __syncthreads();   // u in bB
        {
            AFrag fWv2 = load_afrag(wsW, t * 5 + 4, wv, lane);
            f32x4 ret[4];
            gemm64s<2>(fWv2, bB, bB + 8192, nullptr, nullptr, nullptr, lane, wv, ret);
            __syncthreads();   // all waves done reading u before bB is overwritten
            const f32x4 bvec = *(const f32x4*)(bv2 + t * 64 + 16 * wv + 4 * q);
#pragma unroll
            for (int nt = 0; nt < 4; ++nt) {
                bf16x4 oh, ol;
#pragma unroll
                for (int rr = 0; rr < 4; ++rr) {
                    master[nt][rr] += ret[nt][rr] + bvec[rr];
                    __bf16 h = (__bf16)master[nt][rr];
                    oh[rr] = h;
                    ol[rr] = (__bf16)(master[nt][rr] - (float)h);
                }
                const int off = swz(16 * nt + l15, 32 * wv + 8 * q);
                *(bf16x4*)(bX + off) = oh;
                *(bf16x4*)(bB + off) = ol;
            }
            // refresh filter frags for next layer (overlaps with barrier)
            if (t < 2) {
                fWf1 = load_afrag(wsW, (t + 1) * 5 + 1, wv, lane);
                fWf2 = load_afrag(wsW, (t + 1) * 5 + 2, wv, lane);
            }
        }
        __syncthreads();
    }

    // head: D[c][a] = W1t@X (split), y=tanh(D+b1), p=sum_c y*W2, out=sum_a p + 64*b2
    if (wv < 2) {
        AFrag fW1 = load_afrag(wsW, 15, wv, lane);
        const f32x4 b1v = *(const f32x4*)(b1 + 16 * wv + 4 * q);
        const f32x4 w2v = *(const f32x4*)(sW2v + 16 * wv + 4 * q);
#pragma unroll
        for (int nt = 0; nt < 4; ++nt) {
            const int n = 16 * nt + l15;
            const bf16x8 b0h = *(const bf16x8*)(bX + swz(n, 16 * q));
            const bf16x8 b1h = *(const bf16x8*)(bX + swz(n, 64 + 16 * q));
            const bf16x8 b0l = *(const bf16x8*)(bB + swz(n, 16 * q));
            const bf16x8 b1l = *(const bf16x8*)(bB + swz(n, 64 + 16 * q));
            f32x4 c = {0.f, 0.f, 0.f, 0.f};
            c = __builtin_amdgcn_mfma_f32_16x16x32_bf16(fW1.a0h, b0h, c, 0, 0, 0);
            c = __builtin_amdgcn_mfma_f32_16x16x32_bf16(fW1.a1h, b1h, c, 0, 0, 0);
            c = __builtin_amdgcn_mfma_f32_16x16x32_bf16(fW1.a0h, b0l, c, 0, 0, 0);
            c = __builtin_amdgcn_mfma_f32_16x16x32_bf16(fW1.a1h, b1l, c, 0, 0, 0);
            c = __builtin_amdgcn_mfma_f32_16x16x32_bf16(fW1.a0l, b0h, c, 0, 0, 0);
            c = __builtin_amdgcn_mfma_f32_16x16x32_bf16(fW1.a1l, b1h, c, 0, 0, 0);
            float p = 0.f;
#pragma unroll
            for (int rr = 0; rr < 4; ++rr)
                p = fmaf(tanh_fast(c[rr] + b1v[rr]), w2v[rr], p);
            p += __shfl_xor(p, 16);
            p += __shfl_xor(p, 32);
            if (q == 0) sRed[wv * 64 + nt * 16 + l15] = p;
        }
    }
    __syncthreads();
    if (tid < 64) {
        float s = sRed[tid] + sRed[64 + tid];
#pragma unroll
        for (int off = 1; off < 64; off <<= 1) s += __shfl_xor(s, off);
        if (tid == 0) out[b] = s + 64.0f * b2[0];
    }
}

extern "C" void kernel_launch(void* const* d_in, const int* in_sizes, int n_in,
                              void* d_out, int out_size, void* d_ws, size_t ws_size,
                              hipStream_t stream) {
    const float* r    = (const float*)d_in[0];
    const float* v1   = (const float*)d_in[1];
    const float* v2   = (const float*)d_in[2];
    const float* cent = (const float*)d_in[3];
    const float* Wx   = (const float*)d_in[4];
    const float* bx   = (const float*)d_in[5];
    const float* Wf1  = (const float*)d_in[6];
    const float* bf1  = (const float*)d_in[7];
    const float* Wf2  = (const float*)d_in[8];
    const float* bf2  = (const float*)d_in[9];
    const float* Wv1  = (const float*)d_in[10];
    const float* bv1  = (const float*)d_in[11];
    const float* Wv2  = (const float*)d_in[12];
    const float* bv2  = (const float*)d_in[13];
    const float* W1   = (const float*)d_in[14];
    const float* b1   = (const float*)d_in[15];
    const float* W2   = (const float*)d_in[16];
    const float* b2   = (const float*)d_in[17];
    char* ws = (char*)d_ws;

    prep_weights<<<16, 256, 0, stream>>>(Wx, Wf1, Wf2, Wv1, Wv2, W1, ws);

    const int shmem = 76416;
    (void)hipFuncSetAttribute((const void*)schnet_mfma,
                              hipFuncAttributeMaxDynamicSharedMemorySize, shmem);
    schnet_mfma<<<512, 256, shmem, stream>>>(r, v1, v2, cent, bx, bf1, bf2,
                                             bv1, bv2, b1, W2, b2, ws,
                                             (float*)d_out);
}

// Round 7
// 705.665 us; speedup vs baseline: 3.6533x; 1.3363x over previous
//
#include <hip/hip_runtime.h>

// SchNet fused, bf16-MFMA, hi/lo-split WEIGHTS + X (residual), single-bf16
// activations. One block per batch element, 256 threads (4 waves), 49.6KB LDS
// -> 3 blocks/CU. 2 barriers per i-iteration:
//   [G1: h1 = tanh(Wf1 @ rbf)] bar [G2-epilogue cfconv -> v[i]  ||  rbf(i+1)] bar
// h2 never touches LDS: GEMM2's C-fragment (lane holds 4 feats x 4 j) is
// tanh'd, multiplied by Xl[j][f] and shfl-reduced over the 16-lane group.
// Weights: prep_weights emits per-(mat,wave,lane) A-fragments (hi+lo) in d_ws;
// loaded global->VGPR (L2-resident), never staged in LDS.

typedef __attribute__((ext_vector_type(8))) __bf16 bf16x8;
typedef __attribute__((ext_vector_type(4))) __bf16 bf16x4;
typedef __attribute__((ext_vector_type(4))) float  f32x4;

__device__ __forceinline__ int swz(int row, int byteoff) {
    return row * 128 + (byteoff ^ ((row & 7) << 4));
}

__device__ __forceinline__ float tanh_fast(float x) {
    // tanh(x) = 1 - 2/(exp2(2x/ln2)+1); exact at +/-inf (rcp(inf)=0).
    float t = exp2f(2.88539008f * x);
    return fmaf(-2.0f, __builtin_amdgcn_rcpf(t + 1.0f), 1.0f);
}

struct AFrag { bf16x8 a0h, a1h, a0l, a1l; };

__device__ __forceinline__ AFrag load_afrag(const char* wsW, int mat, int wv, int lane) {
    const char* p = wsW + mat * 16384 + wv * 2048 + lane * 32;
    AFrag f;
    f.a0h = *(const bf16x8*)(p);
    f.a1h = *(const bf16x8*)(p + 16);
    f.a0l = *(const bf16x8*)(p + 8192);
    f.a1l = *(const bf16x8*)(p + 8192 + 16);
    return f;
}

// D[m=f_out][n=row] = A(split) * B. A from frag regs; B hi (+optional lo) in LDS.
// EPI 0: +bias, no act, bf16 store    EPI 1: +bias, tanh, bf16 store
// EPI 2: raw acc -> ret
template <int EPI, bool BSPLIT>
__device__ __forceinline__ void gemm64(const AFrag& A, const char* Bhi, const char* Blo,
                                       const float* __restrict__ bias,
                                       char* Out, int lane, int wv, f32x4* ret) {
    const int l15 = lane & 15, q = lane >> 4;
    f32x4 acc[4];
#pragma unroll
    for (int nt = 0; nt < 4; ++nt) {
        const int n = 16 * nt + l15;
        const bf16x8 b0h = *(const bf16x8*)(Bhi + swz(n, 16 * q));
        const bf16x8 b1h = *(const bf16x8*)(Bhi + swz(n, 64 + 16 * q));
        f32x4 c = {0.f, 0.f, 0.f, 0.f};
        c = __builtin_amdgcn_mfma_f32_16x16x32_bf16(A.a0h, b0h, c, 0, 0, 0);
        c = __builtin_amdgcn_mfma_f32_16x16x32_bf16(A.a1h, b1h, c, 0, 0, 0);
        c = __builtin_amdgcn_mfma_f32_16x16x32_bf16(A.a0l, b0h, c, 0, 0, 0);
        c = __builtin_amdgcn_mfma_f32_16x16x32_bf16(A.a1l, b1h, c, 0, 0, 0);
        if (BSPLIT) {
            const bf16x8 b0l = *(const bf16x8*)(Blo + swz(n, 16 * q));
            const bf16x8 b1l = *(const bf16x8*)(Blo + swz(n, 64 + 16 * q));
            c = __builtin_amdgcn_mfma_f32_16x16x32_bf16(A.a0h, b0l, c, 0, 0, 0);
            c = __builtin_amdgcn_mfma_f32_16x16x32_bf16(A.a1h, b1l, c, 0, 0, 0);
        }
        acc[nt] = c;
    }
    if (EPI == 2) {
#pragma unroll
        for (int nt = 0; nt < 4; ++nt) ret[nt] = acc[nt];
        return;
    }
    const f32x4 bv = *(const f32x4*)(bias + 16 * wv + 4 * q);
#pragma unroll
    for (int nt = 0; nt < 4; ++nt) {
        const int n = 16 * nt + l15;
        bf16x4 oh;
#pragma unroll
        for (int r = 0; r < 4; ++r) {
            float v = acc[nt][r] + bv[r];
            if (EPI == 1) v = tanh_fast(v);
            oh[r] = (__bf16)v;
        }
        *(bf16x4*)(Out + swz(n, 32 * wv + 8 * q)) = oh;
    }
}

// Emit A-fragments (hi+lo) for all 16 matrices into ws (16 * 16384 B).
// mat m<15: t=m/5, s=m%5 {Wx,Wf1,Wf2,Wv1,Wv2}; m=15: W1 (64x32, rows>=32 pad 0).
__global__ void prep_weights(const float* __restrict__ Wx, const float* __restrict__ Wf1,
                             const float* __restrict__ Wf2, const float* __restrict__ Wv1,
                             const float* __restrict__ Wv2, const float* __restrict__ W1,
                             char* __restrict__ ws) {
    const int m = blockIdx.x;
    const int tid = threadIdx.x;
    const int wv = tid >> 6, lane = tid & 63;
    const int l15 = lane & 15, q = lane >> 4;
    const int m_row = 16 * wv + l15;
    const float* src;
    int wcols;
    if (m < 15) {
        const int t = m / 5, s = m % 5;
        src = (s == 0 ? Wx : s == 1 ? Wf1 : s == 2 ? Wf2 : s == 3 ? Wv1 : Wv2) + t * 4096;
        wcols = 64;
    } else {
        src = W1;
        wcols = 32;
    }
    char* base = ws + m * 16384 + wv * 2048 + lane * 32;
#pragma unroll
    for (int kc = 0; kc < 2; ++kc) {
        bf16x8 hi, lo;
#pragma unroll
        for (int e = 0; e < 8; ++e) {
            const int k = 32 * kc + 8 * q + e;
            float val = (m_row < wcols) ? src[k * wcols + m_row] : 0.0f;
            __bf16 h = (__bf16)val;
            hi[e] = h;
            lo[e] = (__bf16)(val - (float)h);
        }
        *(bf16x8*)(base + kc * 16) = hi;
        *(bf16x8*)(base + 8192 + kc * 16) = lo;
    }
}

__global__ __launch_bounds__(256, 3) void schnet_mfma(
    const float* __restrict__ r,   const float* __restrict__ v1g,
    const float* __restrict__ v2g, const float* __restrict__ cent,
    const float* __restrict__ bx,  const float* __restrict__ bf1,
    const float* __restrict__ bf2, const float* __restrict__ bv1,
    const float* __restrict__ bv2, const float* __restrict__ b1,
    const float* __restrict__ W2,  const float* __restrict__ b2,
    const char* __restrict__ wsW,  float* __restrict__ out) {
    extern __shared__ char smem[];
    char* bX   = smem;                        // 8192  X hi   [atom][f]
    char* bXlo = smem + 8192;                 // 8192  X lo
    char* bXl  = smem + 16384;                // 8192  Xl hi  [atom][f]
    char* bV   = smem + 24576;                // 8192  v hi   [atom][f]
    char* bA   = smem + 32768;                // 8192  rbf hi [j][k]
    char* bB   = smem + 40960;                // 8192  h1/u hi [row][f]
    float* sPos  = (float*)(smem + 49152);    // [3][64] planar, 768B
    float* sCent = (float*)(smem + 49920);    // 256B
    float* sRed  = (float*)(smem + 50176);    // [2][64] f32, 512B
    float* sW2v  = (float*)(smem + 50688);    // 128B  -> total 50816

    const int tid = threadIdx.x;
    const int lane = tid & 63, wv = tid >> 6;
    const int l15 = lane & 15, q = lane >> 4;
    const int b = blockIdx.x;

    if (tid < 192) sPos[(tid % 3) * 64 + tid / 3] = r[b * 192 + tid];
    if (tid < 64) sCent[tid] = cent[tid];
    if (tid < 32) sW2v[tid] = W2[tid];

    AFrag fWf1 = load_afrag(wsW, 1, wv, lane);
    AFrag fWf2 = load_afrag(wsW, 2, wv, lane);

    // X master init (fp32 regs; ownership == Wv2-fragment) + hi/lo to LDS
    f32x4 master[4];
    {
        const f32x4 a1v = *(const f32x4*)(v1g + 16 * wv + 4 * q);
        const f32x4 a2v = *(const f32x4*)(v2g + 16 * wv + 4 * q);
#pragma unroll
        for (int nt = 0; nt < 4; ++nt) {
            const bool isv1 = (nt == 0) && (l15 < 2);
            bf16x4 oh, ol;
#pragma unroll
            for (int rr = 0; rr < 4; ++rr) {
                master[nt][rr] = isv1 ? a1v[rr] : a2v[rr];
                __bf16 h = (__bf16)master[nt][rr];
                oh[rr] = h;
                ol[rr] = (__bf16)(master[nt][rr] - (float)h);
            }
            const int off = swz(16 * nt + l15, 32 * wv + 8 * q);
            *(bf16x4*)(bX + off) = oh;
            *(bf16x4*)(bXlo + off) = ol;
        }
    }
    __syncthreads();

    for (int t = 0; t < 3; ++t) {
        {   // phase: Xl = X@Wx + bx (bf16)  ||  rbf(i=0) -> bA
            AFrag fWx = load_afrag(wsW, t * 5 + 0, wv, lane);
            gemm64<0, true>(fWx, bX, bXlo, bx + t * 64, bXl, lane, wv, nullptr);
            const int j = lane;
            const float dx = sPos[j] - sPos[0];
            const float dy = sPos[64 + j] - sPos[64];
            const float dz = sPos[128 + j] - sPos[128];
            const float d = sqrtf(dx * dx + dy * dy + dz * dz);
            bf16x8 h0, h1v;
#pragma unroll
            for (int e = 0; e < 8; ++e) {
                float x0 = d - sCent[wv * 16 + e];
                float x1 = d - sCent[wv * 16 + 8 + e];
                h0[e]  = (__bf16)exp2f(-14.4269504f * x0 * x0);
                h1v[e] = (__bf16)exp2f(-14.4269504f * x1 * x1);
            }
            *(bf16x8*)(bA + swz(j, 32 * wv)) = h0;
            *(bf16x8*)(bA + swz(j, 32 * wv + 16)) = h1v;
        }
        __syncthreads();

        const f32x4 bf2v = *(const f32x4*)(bf2 + t * 64 + 16 * wv + 4 * q);
        for (int i = 0; i < 64; ++i) {
            // phase 1: h1 = tanh(Wf1 @ rbf + bf1) -> bB
            gemm64<1, false>(fWf1, bA, nullptr, bf1 + t * 64, bB, lane, wv, nullptr);
            __syncthreads();
            // phase 2: h2 in-register + cfconv -> bV[i]   ||   rbf(i+1) -> bA
            {
                f32x4 ret[4];
                gemm64<2, false>(fWf2, bB, nullptr, nullptr, nullptr, lane, wv, ret);
                float ts0 = 0.f, ts1 = 0.f, ts2 = 0.f, ts3 = 0.f;
#pragma unroll
                for (int nt = 0; nt < 4; ++nt) {
                    const int j = 16 * nt + l15;
                    const bf16x4 xl = *(const bf16x4*)(bXl + swz(j, 32 * wv + 8 * q));
                    const bool valid = (j != i);
                    const float x0 = valid ? (float)xl[0] : 0.f;
                    const float x1 = valid ? (float)xl[1] : 0.f;
                    const float x2 = valid ? (float)xl[2] : 0.f;
                    const float x3 = valid ? (float)xl[3] : 0.f;
                    ts0 = fmaf(tanh_fast(ret[nt][0] + bf2v[0]), x0, ts0);
                    ts1 = fmaf(tanh_fast(ret[nt][1] + bf2v[1]), x1, ts1);
                    ts2 = fmaf(tanh_fast(ret[nt][2] + bf2v[2]), x2, ts2);
                    ts3 = fmaf(tanh_fast(ret[nt][3] + bf2v[3]), x3, ts3);
                }
#pragma unroll
                for (int m = 1; m < 16; m <<= 1) {
                    ts0 += __shfl_xor(ts0, m);
                    ts1 += __shfl_xor(ts1, m);
                    ts2 += __shfl_xor(ts2, m);
                    ts3 += __shfl_xor(ts3, m);
                }
                if (l15 == 0) {
                    bf16x4 o;
                    o[0] = (__bf16)ts0; o[1] = (__bf16)ts1;
                    o[2] = (__bf16)ts2; o[3] = (__bf16)ts3;
                    *(bf16x4*)(bV + swz(i, 32 * wv + 8 * q)) = o;
                }
            }
            if (i < 63) {   // rbf(i+1), independent of phase-2 buffers
                const int ii = i + 1;
                const int j = lane;
                const float dx = sPos[j] - sPos[ii];
                const float dy = sPos[64 + j] - sPos[64 + ii];
                const float dz = sPos[128 + j] - sPos[128 + ii];
                const float d = sqrtf(dx * dx + dy * dy + dz * dz);
                bf16x8 h0, h1v;
#pragma unroll
                for (int e = 0; e < 8; ++e) {
                    float x0 = d - sCent[wv * 16 + e];
                    float x1 = d - sCent[wv * 16 + 8 + e];
                    h0[e]  = (__bf16)exp2f(-14.4269504f * x0 * x0);
                    h1v[e] = (__bf16)exp2f(-14.4269504f * x1 * x1);
                }
                *(bf16x8*)(bA + swz(j, 32 * wv)) = h0;
                *(bf16x8*)(bA + swz(j, 32 * wv + 16)) = h1v;
            }
            __syncthreads();
        }

        // u = tanh(v @ Wv1 + bv1) -> bB
        {
            AFrag fWv1 = load_afrag(wsW, t * 5 + 3, wv, lane);
            gemm64<1, false>(fWv1, bV, nullptr, bv1 + t * 64, bB, lane, wv, nullptr);
        }
        __syncthreads();
        // X += u @ Wv2 + bv2 (fp32 master), refresh bX/bXlo
        {
            AFrag fWv2 = load_afrag(wsW, t * 5 + 4, wv, lane);
            f32x4 ret[4];
            gemm64<2, false>(fWv2, bB, nullptr, nullptr, nullptr, lane, wv, ret);
            const f32x4 bvec = *(const f32x4*)(bv2 + t * 64 + 16 * wv + 4 * q);
#pragma unroll
            for (int nt = 0; nt < 4; ++nt) {
                bf16x4 oh, ol;
#pragma unroll
                for (int rr = 0; rr < 4; ++rr) {
                    master[nt][rr] += ret[nt][rr] + bvec[rr];
                    __bf16 h = (__bf16)master[nt][rr];
                    oh[rr] = h;
                    ol[rr] = (__bf16)(master[nt][rr] - (float)h);
                }
                const int off = swz(16 * nt + l15, 32 * wv + 8 * q);
                *(bf16x4*)(bX + off) = oh;
                *(bf16x4*)(bXlo + off) = ol;
            }
            if (t < 2) {
                fWf1 = load_afrag(wsW, (t + 1) * 5 + 1, wv, lane);
                fWf2 = load_afrag(wsW, (t + 1) * 5 + 2, wv, lane);
            }
        }
        __syncthreads();
    }

    // head: D[c][a] = W1t @ X (split B), y=tanh(D+b1), p=sum_c y*W2, out=sum_a p + 64*b2
    if (wv < 2) {
        AFrag fW1 = load_afrag(wsW, 15, wv, lane);
        const f32x4 b1v = *(const f32x4*)(b1 + 16 * wv + 4 * q);
        const f32x4 w2v = *(const f32x4*)(sW2v + 16 * wv + 4 * q);
#pragma unroll
        for (int nt = 0; nt < 4; ++nt) {
            const int n = 16 * nt + l15;
            const bf16x8 b0h = *(const bf16x8*)(bX + swz(n, 16 * q));
            const bf16x8 b1h = *(const bf16x8*)(bX + swz(n, 64 + 16 * q));
            const bf16x8 b0l = *(const bf16x8*)(bXlo + swz(n, 16 * q));
            const bf16x8 b1l = *(const bf16x8*)(bXlo + swz(n, 64 + 16 * q));
            f32x4 c = {0.f, 0.f, 0.f, 0.f};
            c = __builtin_amdgcn_mfma_f32_16x16x32_bf16(fW1.a0h, b0h, c, 0, 0, 0);
            c = __builtin_amdgcn_mfma_f32_16x16x32_bf16(fW1.a1h, b1h, c, 0, 0, 0);
            c = __builtin_amdgcn_mfma_f32_16x16x32_bf16(fW1.a0h, b0l, c, 0, 0, 0);
            c = __builtin_amdgcn_mfma_f32_16x16x32_bf16(fW1.a1h, b1l, c, 0, 0, 0);
            c = __builtin_amdgcn_mfma_f32_16x16x32_bf16(fW1.a0l, b0h, c, 0, 0, 0);
            c = __builtin_amdgcn_mfma_f32_16x16x32_bf16(fW1.a1l, b1h, c, 0, 0, 0);
            float p = 0.f;
#pragma unroll
            for (int rr = 0; rr < 4; ++rr)
                p = fmaf(tanh_fast(c[rr] + b1v[rr]), w2v[rr], p);
            p += __shfl_xor(p, 16);
            p += __shfl_xor(p, 32);
            if (q == 0) sRed[wv * 64 + nt * 16 + l15] = p;
        }
    }
    __syncthreads();
    if (tid < 64) {
        float s = sRed[tid] + sRed[64 + tid];
#pragma unroll
        for (int off = 1; off < 64; off <<= 1) s += __shfl_xor(s, off);
        if (tid == 0) out[b] = s + 64.0f * b2[0];
    }
}

extern "C" void kernel_launch(void* const* d_in, const int* in_sizes, int n_in,
                              void* d_out, int out_size, void* d_ws, size_t ws_size,
                              hipStream_t stream) {
    const float* r    = (const float*)d_in[0];
    const float* v1   = (const float*)d_in[1];
    const float* v2   = (const float*)d_in[2];
    const float* cent = (const float*)d_in[3];
    const float* Wx   = (const float*)d_in[4];
    const float* bx   = (const float*)d_in[5];
    const float* Wf1  = (const float*)d_in[6];
    const float* bf1  = (const float*)d_in[7];
    const float* Wf2  = (const float*)d_in[8];
    const float* bf2  = (const float*)d_in[9];
    const float* Wv1  = (const float*)d_in[10];
    const float* bv1  = (const float*)d_in[11];
    const float* Wv2  = (const float*)d_in[12];
    const float* bv2  = (const float*)d_in[13];
    const float* W1   = (const float*)d_in[14];
    const float* b1   = (const float*)d_in[15];
    const float* W2   = (const float*)d_in[16];
    const float* b2   = (const float*)d_in[17];
    char* ws = (char*)d_ws;

    prep_weights<<<16, 256, 0, stream>>>(Wx, Wf1, Wf2, Wv1, Wv2, W1, ws);

    const int shmem = 50816;
    (void)hipFuncSetAttribute((const void*)schnet_mfma,
                              hipFuncAttributeMaxDynamicSharedMemorySize, shmem);
    schnet_mfma<<<512, 256, shmem, stream>>>(r, v1, v2, cent, bx, bf1, bf2,
                                             bv1, bv2, b1, W2, b2, ws,
                                             (float*)d_out);
}

// Round 8
// 662.553 us; speedup vs baseline: 3.8910x; 1.0651x over previous
//
#include <hip/hip_runtime.h>

// SchNet, multi-kernel bf16-MFMA pipeline.
// prep_weights (16 blk) -> init_x (512 blk) -> 3x { A (1024 blk), B (512 blk) }.
// A(b,ih): restage X[b] (global fp32 -> hi/lo LDS), Xl = Wx@X, then 32 i's:
//   rbf -> h1 = tanh(Wf1@rbf) -> h2-in-reg cfconv -> v[i] to global bf16.
//   Grid 1024 = 4 blocks/CU (~16 waves/CU) vs R7's grid-limited 2.
// B(b): v -> u = tanh(Wv1@v) -> X += Wv2@u + bv2 (global fp32 master);
//   at t==2 also the W1/W2 head -> out.
// Weights hi/lo-split per-(mat,wave,lane) A-fragments in d_ws (L2-resident).
// d_ws: [0,256K) weight frags; [256K,8.6M) X fp32; [8.6M,12.9M) v bf16.

typedef __attribute__((ext_vector_type(8))) __bf16 bf16x8;
typedef __attribute__((ext_vector_type(4))) __bf16 bf16x4;
typedef __attribute__((ext_vector_type(4))) float  f32x4;

#define WS_X 262144
#define WS_V 8650752

__device__ __forceinline__ int swz(int row, int byteoff) {
    return row * 128 + (byteoff ^ ((row & 7) << 4));
}

__device__ __forceinline__ float tanh_fast(float x) {
    float t = exp2f(2.88539008f * x);
    return fmaf(-2.0f, __builtin_amdgcn_rcpf(t + 1.0f), 1.0f);
}

struct AFrag { bf16x8 a0h, a1h, a0l, a1l; };

__device__ __forceinline__ AFrag load_afrag(const char* wsW, int mat, int wv, int lane) {
    const char* p = wsW + mat * 16384 + wv * 2048 + lane * 32;
    AFrag f;
    f.a0h = *(const bf16x8*)(p);
    f.a1h = *(const bf16x8*)(p + 16);
    f.a0l = *(const bf16x8*)(p + 8192);
    f.a1l = *(const bf16x8*)(p + 8192 + 16);
    return f;
}

// D[m=f_out][n=row] = A(split) * B. EPI 0: +bias store; 1: +bias tanh store; 2: ret.
template <int EPI, bool BSPLIT>
__device__ __forceinline__ void gemm64(const AFrag& A, const char* Bhi, const char* Blo,
                                       const float* __restrict__ bias,
                                       char* Out, int lane, int wv, f32x4* ret) {
    const int l15 = lane & 15, q = lane >> 4;
    f32x4 acc[4];
#pragma unroll
    for (int nt = 0; nt < 4; ++nt) {
        const int n = 16 * nt + l15;
        const bf16x8 b0h = *(const bf16x8*)(Bhi + swz(n, 16 * q));
        const bf16x8 b1h = *(const bf16x8*)(Bhi + swz(n, 64 + 16 * q));
        f32x4 c = {0.f, 0.f, 0.f, 0.f};
        c = __builtin_amdgcn_mfma_f32_16x16x32_bf16(A.a0h, b0h, c, 0, 0, 0);
        c = __builtin_amdgcn_mfma_f32_16x16x32_bf16(A.a1h, b1h, c, 0, 0, 0);
        c = __builtin_amdgcn_mfma_f32_16x16x32_bf16(A.a0l, b0h, c, 0, 0, 0);
        c = __builtin_amdgcn_mfma_f32_16x16x32_bf16(A.a1l, b1h, c, 0, 0, 0);
        if (BSPLIT) {
            const bf16x8 b0l = *(const bf16x8*)(Blo + swz(n, 16 * q));
            const bf16x8 b1l = *(const bf16x8*)(Blo + swz(n, 64 + 16 * q));
            c = __builtin_amdgcn_mfma_f32_16x16x32_bf16(A.a0h, b0l, c, 0, 0, 0);
            c = __builtin_amdgcn_mfma_f32_16x16x32_bf16(A.a1h, b1l, c, 0, 0, 0);
        }
        acc[nt] = c;
    }
    if (EPI == 2) {
#pragma unroll
        for (int nt = 0; nt < 4; ++nt) ret[nt] = acc[nt];
        return;
    }
    const f32x4 bv = *(const f32x4*)(bias + 16 * wv + 4 * q);
#pragma unroll
    for (int nt = 0; nt < 4; ++nt) {
        const int n = 16 * nt + l15;
        bf16x4 oh;
#pragma unroll
        for (int r = 0; r < 4; ++r) {
            float v = acc[nt][r] + bv[r];
            if (EPI == 1) v = tanh_fast(v);
            oh[r] = (__bf16)v;
        }
        *(bf16x4*)(Out + swz(n, 32 * wv + 8 * q)) = oh;
    }
}

__global__ void prep_weights(const float* __restrict__ Wx, const float* __restrict__ Wf1,
                             const float* __restrict__ Wf2, const float* __restrict__ Wv1,
                             const float* __restrict__ Wv2, const float* __restrict__ W1,
                             char* __restrict__ ws) {
    const int m = blockIdx.x;
    const int tid = threadIdx.x;
    const int wv = tid >> 6, lane = tid & 63;
    const int l15 = lane & 15, q = lane >> 4;
    const int m_row = 16 * wv + l15;
    const float* src;
    int wcols;
    if (m < 15) {
        const int t = m / 5, s = m % 5;
        src = (s == 0 ? Wx : s == 1 ? Wf1 : s == 2 ? Wf2 : s == 3 ? Wv1 : Wv2) + t * 4096;
        wcols = 64;
    } else {
        src = W1;
        wcols = 32;
    }
    char* base = ws + m * 16384 + wv * 2048 + lane * 32;
#pragma unroll
    for (int kc = 0; kc < 2; ++kc) {
        bf16x8 hi, lo;
#pragma unroll
        for (int e = 0; e < 8; ++e) {
            const int k = 32 * kc + 8 * q + e;
            float val = (m_row < wcols) ? src[k * wcols + m_row] : 0.0f;
            __bf16 h = (__bf16)val;
            hi[e] = h;
            lo[e] = (__bf16)(val - (float)h);
        }
        *(bf16x8*)(base + kc * 16) = hi;
        *(bf16x8*)(base + 8192 + kc * 16) = lo;
    }
}

__global__ __launch_bounds__(256) void init_x(const float* __restrict__ v1g,
                                              const float* __restrict__ v2g,
                                              float* __restrict__ gX) {
    const int b = blockIdx.x, tid = threadIdx.x;
    const int a = tid >> 2, f0 = (tid & 3) << 4;
    const float* src = (a < 2) ? v1g : v2g;
    f32x4 vv0 = *(const f32x4*)(src + f0);
    f32x4 vv1 = *(const f32x4*)(src + f0 + 4);
    f32x4 vv2 = *(const f32x4*)(src + f0 + 8);
    f32x4 vv3 = *(const f32x4*)(src + f0 + 12);
    float* dst = gX + b * 4096 + a * 64 + f0;
    *(f32x4*)(dst)      = vv0;
    *(f32x4*)(dst + 4)  = vv1;
    *(f32x4*)(dst + 8)  = vv2;
    *(f32x4*)(dst + 12) = vv3;
}

// A: grid 1024 = (b, ih). 25.6KB LDS -> 4+ blocks/CU.
__global__ __launch_bounds__(256, 4) void schnet_a(
    const float* __restrict__ r,   const float* __restrict__ cent,
    const float* __restrict__ bx,  const float* __restrict__ bf1,
    const float* __restrict__ bf2, const char* __restrict__ wsW,
    const float* __restrict__ gX,  __bf16* __restrict__ gV, int t) {
    extern __shared__ char smem[];
    char* bA  = smem;                       // 8192  X-hi staging, then rbf
    char* bB  = smem + 8192;                // 8192  X-lo staging, then h1
    char* bXl = smem + 16384;               // 8192  Xl bf16 [atom][f]
    float* sPos  = (float*)(smem + 24576);  // [3][64]
    float* sCent = (float*)(smem + 25344);  // 256B -> total 25600

    const int tid = threadIdx.x;
    const int lane = tid & 63, wv = tid >> 6;
    const int l15 = lane & 15, q = lane >> 4;
    const int b = blockIdx.x >> 1, ih = blockIdx.x & 1;

    if (tid < 192) sPos[(tid % 3) * 64 + tid / 3] = r[b * 192 + tid];
    if (tid < 64) sCent[tid] = cent[tid];

    const AFrag fWx  = load_afrag(wsW, t * 5 + 0, wv, lane);
    const AFrag fWf1 = load_afrag(wsW, t * 5 + 1, wv, lane);
    const AFrag fWf2 = load_afrag(wsW, t * 5 + 2, wv, lane);

    {   // stage X[b] fp32 -> hi/lo planes in bA/bB
        const int a = tid >> 2, f0 = (tid & 3) << 4;
        const f32x4* src = (const f32x4*)(gX + b * 4096 + a * 64 + f0);
        bf16x8 h0, h1, l0, l1;
#pragma unroll
        for (int c = 0; c < 2; ++c) {
            const f32x4 s = src[c];
#pragma unroll
            for (int e = 0; e < 4; ++e) {
                __bf16 hh = (__bf16)s[e];
                h0[c * 4 + e] = hh;
                l0[c * 4 + e] = (__bf16)(s[e] - (float)hh);
            }
        }
#pragma unroll
        for (int c = 0; c < 2; ++c) {
            const f32x4 s = src[2 + c];
#pragma unroll
            for (int e = 0; e < 4; ++e) {
                __bf16 hh = (__bf16)s[e];
                h1[c * 4 + e] = hh;
                l1[c * 4 + e] = (__bf16)(s[e] - (float)hh);
            }
        }
        const int o0 = swz(a, 2 * f0), o1 = swz(a, 2 * f0 + 16);
        *(bf16x8*)(bA + o0) = h0;
        *(bf16x8*)(bA + o1) = h1;
        *(bf16x8*)(bB + o0) = l0;
        *(bf16x8*)(bB + o1) = l1;
    }
    __syncthreads();
    gemm64<0, true>(fWx, bA, bB, bx + t * 64, bXl, lane, wv, nullptr);
    __syncthreads();

    const int i0 = ih * 32;
    {   // rbf(i0) -> bA
        const int j = lane;
        const float dx = sPos[j] - sPos[i0];
        const float dy = sPos[64 + j] - sPos[64 + i0];
        const float dz = sPos[128 + j] - sPos[128 + i0];
        const float d = sqrtf(dx * dx + dy * dy + dz * dz);
        bf16x8 h0, h1v;
#pragma unroll
        for (int e = 0; e < 8; ++e) {
            float x0 = d - sCent[wv * 16 + e];
            float x1 = d - sCent[wv * 16 + 8 + e];
            h0[e]  = (__bf16)exp2f(-14.4269504f * x0 * x0);
            h1v[e] = (__bf16)exp2f(-14.4269504f * x1 * x1);
        }
        *(bf16x8*)(bA + swz(j, 32 * wv)) = h0;
        *(bf16x8*)(bA + swz(j, 32 * wv + 16)) = h1v;
    }
    __syncthreads();

    const f32x4 bf2v = *(const f32x4*)(bf2 + t * 64 + 16 * wv + 4 * q);
    for (int ii = 0; ii < 32; ++ii) {
        const int i = i0 + ii;
        // phase 1: h1 = tanh(Wf1 @ rbf + bf1) -> bB
        gemm64<1, false>(fWf1, bA, nullptr, bf1 + t * 64, bB, lane, wv, nullptr);
        __syncthreads();
        // phase 2: h2 in-reg + cfconv -> gV[b][i]   ||   rbf(i+1) -> bA
        {
            f32x4 ret[4];
            gemm64<2, false>(fWf2, bB, nullptr, nullptr, nullptr, lane, wv, ret);
            float ts0 = 0.f, ts1 = 0.f, ts2 = 0.f, ts3 = 0.f;
#pragma unroll
            for (int nt = 0; nt < 4; ++nt) {
                const int j = 16 * nt + l15;
                const bf16x4 xl = *(const bf16x4*)(bXl + swz(j, 32 * wv + 8 * q));
                const bool valid = (j != i);
                const float x0 = valid ? (float)xl[0] : 0.f;
                const float x1 = valid ? (float)xl[1] : 0.f;
                const float x2 = valid ? (float)xl[2] : 0.f;
                const float x3 = valid ? (float)xl[3] : 0.f;
                ts0 = fmaf(tanh_fast(ret[nt][0] + bf2v[0]), x0, ts0);
                ts1 = fmaf(tanh_fast(ret[nt][1] + bf2v[1]), x1, ts1);
                ts2 = fmaf(tanh_fast(ret[nt][2] + bf2v[2]), x2, ts2);
                ts3 = fmaf(tanh_fast(ret[nt][3] + bf2v[3]), x3, ts3);
            }
#pragma unroll
            for (int m = 1; m < 16; m <<= 1) {
                ts0 += __shfl_xor(ts0, m);
                ts1 += __shfl_xor(ts1, m);
                ts2 += __shfl_xor(ts2, m);
                ts3 += __shfl_xor(ts3, m);
            }
            if (l15 == 0) {
                bf16x4 o;
                o[0] = (__bf16)ts0; o[1] = (__bf16)ts1;
                o[2] = (__bf16)ts2; o[3] = (__bf16)ts3;
                *(bf16x4*)(gV + (b * 64 + i) * 64 + 16 * wv + 4 * q) = o;
            }
        }
        if (ii < 31) {
            const int inext = i + 1;
            const int j = lane;
            const float dx = sPos[j] - sPos[inext];
            const float dy = sPos[64 + j] - sPos[64 + inext];
            const float dz = sPos[128 + j] - sPos[128 + inext];
            const float d = sqrtf(dx * dx + dy * dy + dz * dz);
            bf16x8 h0, h1v;
#pragma unroll
            for (int e = 0; e < 8; ++e) {
                float x0 = d - sCent[wv * 16 + e];
                float x1 = d - sCent[wv * 16 + 8 + e];
                h0[e]  = (__bf16)exp2f(-14.4269504f * x0 * x0);
                h1v[e] = (__bf16)exp2f(-14.4269504f * x1 * x1);
            }
            *(bf16x8*)(bA + swz(j, 32 * wv)) = h0;
            *(bf16x8*)(bA + swz(j, 32 * wv + 16)) = h1v;
        }
        __syncthreads();
    }
}

// B: grid 512. v -> u -> X update (+ head at t==2). 33.4KB LDS.
__global__ __launch_bounds__(256, 2) void schnet_b(
    const float* __restrict__ bv1, const float* __restrict__ bv2,
    const float* __restrict__ b1,  const float* __restrict__ W2,
    const float* __restrict__ b2,  const char* __restrict__ wsW,
    float* __restrict__ gX, const __bf16* __restrict__ gV,
    float* __restrict__ out, int t) {
    extern __shared__ char smem[];
    char* bV   = smem;                      // 8192 v bf16
    char* bB   = smem + 8192;               // 8192 u bf16
    char* bX   = smem + 16384;              // 8192 X hi (head)
    char* bXlo = smem + 24576;              // 8192 X lo (head)
    float* sRed = (float*)(smem + 32768);   // [2][64]
    float* sW2v = (float*)(smem + 33280);   // 128B -> total 33408

    const int tid = threadIdx.x;
    const int lane = tid & 63, wv = tid >> 6;
    const int l15 = lane & 15, q = lane >> 4;
    const int b = blockIdx.x;

    if (tid < 32) sW2v[tid] = W2[tid];

    {   // stage v -> bV
        const int a = tid >> 2, f0 = (tid & 3) << 4;
        const __bf16* src = gV + (b * 64 + a) * 64 + f0;
        const bf16x8 v0 = *(const bf16x8*)(src);
        const bf16x8 v1 = *(const bf16x8*)(src + 8);
        *(bf16x8*)(bV + swz(a, 2 * f0)) = v0;
        *(bf16x8*)(bV + swz(a, 2 * f0 + 16)) = v1;
    }
    __syncthreads();
    {   // u = tanh(Wv1 @ v + bv1) -> bB
        const AFrag fWv1 = load_afrag(wsW, t * 5 + 3, wv, lane);
        gemm64<1, false>(fWv1, bV, nullptr, bv1 + t * 64, bB, lane, wv, nullptr);
    }
    __syncthreads();
    // X += Wv2 @ u + bv2 (global fp32 master)
    f32x4 master[4];
    {
        const AFrag fWv2 = load_afrag(wsW, t * 5 + 4, wv, lane);
        f32x4 ret[4];
        gemm64<2, false>(fWv2, bB, nullptr, nullptr, nullptr, lane, wv, ret);
        const f32x4 bvec = *(const f32x4*)(bv2 + t * 64 + 16 * wv + 4 * q);
#pragma unroll
        for (int nt = 0; nt < 4; ++nt) {
            float* px = gX + b * 4096 + (16 * nt + l15) * 64 + 16 * wv + 4 * q;
            f32x4 m = *(const f32x4*)px;
#pragma unroll
            for (int rr = 0; rr < 4; ++rr) m[rr] += ret[nt][rr] + bvec[rr];
            *(f32x4*)px = m;
            master[nt] = m;
        }
    }

    if (t == 2) {
        // materialize X hi/lo planes for the head
#pragma unroll
        for (int nt = 0; nt < 4; ++nt) {
            bf16x4 oh, ol;
#pragma unroll
            for (int rr = 0; rr < 4; ++rr) {
                __bf16 h = (__bf16)master[nt][rr];
                oh[rr] = h;
                ol[rr] = (__bf16)(master[nt][rr] - (float)h);
            }
            const int off = swz(16 * nt + l15, 32 * wv + 8 * q);
            *(bf16x4*)(bX + off) = oh;
            *(bf16x4*)(bXlo + off) = ol;
        }
        __syncthreads();
        if (wv < 2) {
            const AFrag fW1 = load_afrag(wsW, 15, wv, lane);
            const f32x4 b1v = *(const f32x4*)(b1 + 16 * wv + 4 * q);
            const f32x4 w2v = *(const f32x4*)(sW2v + 16 * wv + 4 * q);
#pragma unroll
            for (int nt = 0; nt < 4; ++nt) {
                const int n = 16 * nt + l15;
                const bf16x8 b0h = *(const bf16x8*)(bX + swz(n, 16 * q));
                const bf16x8 b1h = *(const bf16x8*)(bX + swz(n, 64 + 16 * q));
                const bf16x8 b0l = *(const bf16x8*)(bXlo + swz(n, 16 * q));
                const bf16x8 b1l = *(const bf16x8*)(bXlo + swz(n, 64 + 16 * q));
                f32x4 c = {0.f, 0.f, 0.f, 0.f};
                c = __builtin_amdgcn_mfma_f32_16x16x32_bf16(fW1.a0h, b0h, c, 0, 0, 0);
                c = __builtin_amdgcn_mfma_f32_16x16x32_bf16(fW1.a1h, b1h, c, 0, 0, 0);
                c = __builtin_amdgcn_mfma_f32_16x16x32_bf16(fW1.a0h, b0l, c, 0, 0, 0);
                c = __builtin_amdgcn_mfma_f32_16x16x32_bf16(fW1.a1h, b1l, c, 0, 0, 0);
                c = __builtin_amdgcn_mfma_f32_16x16x32_bf16(fW1.a0l, b0h, c, 0, 0, 0);
                c = __builtin_amdgcn_mfma_f32_16x16x32_bf16(fW1.a1l, b1h, c, 0, 0, 0);
                float p = 0.f;
#pragma unroll
                for (int rr = 0; rr < 4; ++rr)
                    p = fmaf(tanh_fast(c[rr] + b1v[rr]), w2v[rr], p);
                p += __shfl_xor(p, 16);
                p += __shfl_xor(p, 32);
                if (q == 0) sRed[wv * 64 + nt * 16 + l15] = p;
            }
        }
        __syncthreads();
        if (tid < 64) {
            float s = sRed[tid] + sRed[64 + tid];
#pragma unroll
            for (int off = 1; off < 64; off <<= 1) s += __shfl_xor(s, off);
            if (tid == 0) out[b] = s + 64.0f * b2[0];
        }
    }
}

extern "C" void kernel_launch(void* const* d_in, const int* in_sizes, int n_in,
                              void* d_out, int out_size, void* d_ws, size_t ws_size,
                              hipStream_t stream) {
    const float* r    = (const float*)d_in[0];
    const float* v1   = (const float*)d_in[1];
    const float* v2   = (const float*)d_in[2];
    const float* cent = (const float*)d_in[3];
    const float* Wx   = (const float*)d_in[4];
    const float* bx   = (const float*)d_in[5];
    const float* Wf1  = (const float*)d_in[6];
    const float* bf1  = (const float*)d_in[7];
    const float* Wf2  = (const float*)d_in[8];
    const float* bf2  = (const float*)d_in[9];
    const float* Wv1  = (const float*)d_in[10];
    const float* bv1  = (const float*)d_in[11];
    const float* Wv2  = (const float*)d_in[12];
    const float* bv2  = (const float*)d_in[13];
    const float* W1   = (const float*)d_in[14];
    const float* b1   = (const float*)d_in[15];
    const float* W2   = (const float*)d_in[16];
    const float* b2   = (const float*)d_in[17];
    char* ws = (char*)d_ws;
    float*  gX = (float*)(ws + WS_X);
    __bf16* gV = (__bf16*)(ws + WS_V);

    prep_weights<<<16, 256, 0, stream>>>(Wx, Wf1, Wf2, Wv1, Wv2, W1, ws);
    init_x<<<512, 256, 0, stream>>>(v1, v2, gX);

    (void)hipFuncSetAttribute((const void*)schnet_a,
                              hipFuncAttributeMaxDynamicSharedMemorySize, 25600);
    (void)hipFuncSetAttribute((const void*)schnet_b,
                              hipFuncAttributeMaxDynamicSharedMemorySize, 33408);
    for (int t = 0; t < 3; ++t) {
        schnet_a<<<1024, 256, 25600, stream>>>(r, cent, bx, bf1, bf2, ws, gX, gV, t);
        schnet_b<<<512, 256, 33408, stream>>>(bv1, bv2, b1, W2, b2, ws, gX, gV,
                                              (float*)d_out, t);
    }
}

// Round 9
// 501.342 us; speedup vs baseline: 5.1422x; 1.3216x over previous
//
#include <hip/hip_runtime.h>

// SchNet, multi-kernel bf16-MFMA pipeline, native-transcendental edition.
// prep_weights (16 blk) -> init_x (512 blk) -> 3x { A (1024 blk), B (512 blk) }.
// A(b,ih): restage X[b] (global fp32 -> hi/lo LDS), Xl = Wx@X, then 32 i's:
//   rbf -> h1 = tanh(Wf1@rbf) -> h2-in-reg cfconv -> v[i] to global bf16.
// B(b): v -> u = tanh(Wv1@v) -> X += Wv2@u + bv2 (global fp32 master);
//   at t==2 also the W1/W2 head -> out.
// All exp2/sqrt via __builtin_amdgcn_* single-instruction forms (no libcalls).
// Loop-invariant LDS values (own pos, centers, Xl frag, biases) hoisted to
// registers -- the compiler cannot hoist LDS reads across __syncthreads.
// Weights hi/lo-split per-(mat,wave,lane) A-fragments in d_ws (L2-resident).
// d_ws: [0,256K) weight frags; [256K,8.6M) X fp32; [8.6M,12.9M) v bf16.

typedef __attribute__((ext_vector_type(8))) __bf16 bf16x8;
typedef __attribute__((ext_vector_type(4))) __bf16 bf16x4;
typedef __attribute__((ext_vector_type(4))) float  f32x4;

#define WS_X 262144
#define WS_V 8650752

__device__ __forceinline__ int swz(int row, int byteoff) {
    return row * 128 + (byteoff ^ ((row & 7) << 4));
}

__device__ __forceinline__ float fexp2(float x) { return __builtin_amdgcn_exp2f(x); }

__device__ __forceinline__ float tanh_fast(float x) {
    // tanh(x) = 1 - 2/(2^(2x/ln2)+1); exact at +/-inf (rcp(inf)=0).
    float t = fexp2(2.88539008f * x);
    return fmaf(-2.0f, __builtin_amdgcn_rcpf(t + 1.0f), 1.0f);
}

struct AFrag { bf16x8 a0h, a1h, a0l, a1l; };

__device__ __forceinline__ AFrag load_afrag(const char* wsW, int mat, int wv, int lane) {
    const char* p = wsW + mat * 16384 + wv * 2048 + lane * 32;
    AFrag f;
    f.a0h = *(const bf16x8*)(p);
    f.a1h = *(const bf16x8*)(p + 16);
    f.a0l = *(const bf16x8*)(p + 8192);
    f.a1l = *(const bf16x8*)(p + 8192 + 16);
    return f;
}

// D[m=f_out][n=row] = A(split) * B. bv = pre-loaded per-thread bias fragment.
// EPI 0: +bias store; 1: +bias tanh store; 2: raw acc -> ret.
template <int EPI, bool BSPLIT>
__device__ __forceinline__ void gemm64(const AFrag& A, const char* Bhi, const char* Blo,
                                       const f32x4 bv, char* Out,
                                       int lane, int wv, f32x4* ret) {
    const int l15 = lane & 15, q = lane >> 4;
    f32x4 acc[4];
#pragma unroll
    for (int nt = 0; nt < 4; ++nt) {
        const int n = 16 * nt + l15;
        const bf16x8 b0h = *(const bf16x8*)(Bhi + swz(n, 16 * q));
        const bf16x8 b1h = *(const bf16x8*)(Bhi + swz(n, 64 + 16 * q));
        f32x4 c = {0.f, 0.f, 0.f, 0.f};
        c = __builtin_amdgcn_mfma_f32_16x16x32_bf16(A.a0h, b0h, c, 0, 0, 0);
        c = __builtin_amdgcn_mfma_f32_16x16x32_bf16(A.a1h, b1h, c, 0, 0, 0);
        c = __builtin_amdgcn_mfma_f32_16x16x32_bf16(A.a0l, b0h, c, 0, 0, 0);
        c = __builtin_amdgcn_mfma_f32_16x16x32_bf16(A.a1l, b1h, c, 0, 0, 0);
        if (BSPLIT) {
            const bf16x8 b0l = *(const bf16x8*)(Blo + swz(n, 16 * q));
            const bf16x8 b1l = *(const bf16x8*)(Blo + swz(n, 64 + 16 * q));
            c = __builtin_amdgcn_mfma_f32_16x16x32_bf16(A.a0h, b0l, c, 0, 0, 0);
            c = __builtin_amdgcn_mfma_f32_16x16x32_bf16(A.a1h, b1l, c, 0, 0, 0);
        }
        acc[nt] = c;
    }
    if (EPI == 2) {
#pragma unroll
        for (int nt = 0; nt < 4; ++nt) ret[nt] = acc[nt];
        return;
    }
#pragma unroll
    for (int nt = 0; nt < 4; ++nt) {
        const int n = 16 * nt + l15;
        bf16x4 oh;
#pragma unroll
        for (int r = 0; r < 4; ++r) {
            float v = acc[nt][r] + bv[r];
            if (EPI == 1) v = tanh_fast(v);
            oh[r] = (__bf16)v;
        }
        *(bf16x4*)(Out + swz(n, 32 * wv + 8 * q)) = oh;
    }
}

__global__ void prep_weights(const float* __restrict__ Wx, const float* __restrict__ Wf1,
                             const float* __restrict__ Wf2, const float* __restrict__ Wv1,
                             const float* __restrict__ Wv2, const float* __restrict__ W1,
                             char* __restrict__ ws) {
    const int m = blockIdx.x;
    const int tid = threadIdx.x;
    const int wv = tid >> 6, lane = tid & 63;
    const int l15 = lane & 15, q = lane >> 4;
    const int m_row = 16 * wv + l15;
    const float* src;
    int wcols;
    if (m < 15) {
        const int t = m / 5, s = m % 5;
        src = (s == 0 ? Wx : s == 1 ? Wf1 : s == 2 ? Wf2 : s == 3 ? Wv1 : Wv2) + t * 4096;
        wcols = 64;
    } else {
        src = W1;
        wcols = 32;
    }
    char* base = ws + m * 16384 + wv * 2048 + lane * 32;
#pragma unroll
    for (int kc = 0; kc < 2; ++kc) {
        bf16x8 hi, lo;
#pragma unroll
        for (int e = 0; e < 8; ++e) {
            const int k = 32 * kc + 8 * q + e;
            float val = (m_row < wcols) ? src[k * wcols + m_row] : 0.0f;
            __bf16 h = (__bf16)val;
            hi[e] = h;
            lo[e] = (__bf16)(val - (float)h);
        }
        *(bf16x8*)(base + kc * 16) = hi;
        *(bf16x8*)(base + 8192 + kc * 16) = lo;
    }
}

__global__ __launch_bounds__(256) void init_x(const float* __restrict__ v1g,
                                              const float* __restrict__ v2g,
                                              float* __restrict__ gX) {
    const int b = blockIdx.x, tid = threadIdx.x;
    const int a = tid >> 2, f0 = (tid & 3) << 4;
    const float* src = (a < 2) ? v1g : v2g;
    f32x4 vv0 = *(const f32x4*)(src + f0);
    f32x4 vv1 = *(const f32x4*)(src + f0 + 4);
    f32x4 vv2 = *(const f32x4*)(src + f0 + 8);
    f32x4 vv3 = *(const f32x4*)(src + f0 + 12);
    float* dst = gX + b * 4096 + a * 64 + f0;
    *(f32x4*)(dst)      = vv0;
    *(f32x4*)(dst + 4)  = vv1;
    *(f32x4*)(dst + 8)  = vv2;
    *(f32x4*)(dst + 12) = vv3;
}

// A: grid 1024 = (b, ih). 25.6KB LDS, VGPR<=128 -> 4 blocks/CU.
__global__ __launch_bounds__(256, 4) void schnet_a(
    const float* __restrict__ r,   const float* __restrict__ cent,
    const float* __restrict__ bx,  const float* __restrict__ bf1,
    const float* __restrict__ bf2, const char* __restrict__ wsW,
    const float* __restrict__ gX,  __bf16* __restrict__ gV, int t) {
    extern __shared__ char smem[];
    char* bA  = smem;                       // 8192  X-hi staging, then rbf
    char* bB  = smem + 8192;                // 8192  X-lo staging, then h1
    char* bXl = smem + 16384;               // 8192  Xl bf16 [atom][f]
    float* sPos  = (float*)(smem + 24576);  // [3][64]
    float* sCent = (float*)(smem + 25344);  // 256B -> total 25600

    const int tid = threadIdx.x;
    const int lane = tid & 63, wv = tid >> 6;
    const int l15 = lane & 15, q = lane >> 4;
    const int b = blockIdx.x >> 1, ih = blockIdx.x & 1;

    if (tid < 192) sPos[(tid % 3) * 64 + tid / 3] = r[b * 192 + tid];
    if (tid < 64) sCent[tid] = cent[tid];

    const AFrag fWx  = load_afrag(wsW, t * 5 + 0, wv, lane);
    const AFrag fWf1 = load_afrag(wsW, t * 5 + 1, wv, lane);
    const AFrag fWf2 = load_afrag(wsW, t * 5 + 2, wv, lane);
    const f32x4 bxv  = *(const f32x4*)(bx  + t * 64 + 16 * wv + 4 * q);
    const f32x4 bf1v = *(const f32x4*)(bf1 + t * 64 + 16 * wv + 4 * q);
    const f32x4 bf2v = *(const f32x4*)(bf2 + t * 64 + 16 * wv + 4 * q);

    {   // stage X[b] fp32 -> hi/lo planes in bA/bB
        const int a = tid >> 2, f0 = (tid & 3) << 4;
        const f32x4* src = (const f32x4*)(gX + b * 4096 + a * 64 + f0);
        bf16x8 h0, h1, l0, l1;
#pragma unroll
        for (int c = 0; c < 2; ++c) {
            const f32x4 s = src[c];
#pragma unroll
            for (int e = 0; e < 4; ++e) {
                __bf16 hh = (__bf16)s[e];
                h0[c * 4 + e] = hh;
                l0[c * 4 + e] = (__bf16)(s[e] - (float)hh);
            }
        }
#pragma unroll
        for (int c = 0; c < 2; ++c) {
            const f32x4 s = src[2 + c];
#pragma unroll
            for (int e = 0; e < 4; ++e) {
                __bf16 hh = (__bf16)s[e];
                h1[c * 4 + e] = hh;
                l1[c * 4 + e] = (__bf16)(s[e] - (float)hh);
            }
        }
        const int o0 = swz(a, 2 * f0), o1 = swz(a, 2 * f0 + 16);
        *(bf16x8*)(bA + o0) = h0;
        *(bf16x8*)(bA + o1) = h1;
        *(bf16x8*)(bB + o0) = l0;
        *(bf16x8*)(bB + o1) = l1;
    }
    __syncthreads();
    gemm64<0, true>(fWx, bA, bB, bxv, bXl, lane, wv, nullptr);
    __syncthreads();

    // hoist loop-invariants: own position, centers, Xl fragment (values!)
    const float pjx = sPos[lane], pjy = sPos[64 + lane], pjz = sPos[128 + lane];
    float cc[16];
#pragma unroll
    for (int e = 0; e < 16; ++e) cc[e] = sCent[wv * 16 + e];
    float xlf[4][4];
#pragma unroll
    for (int nt = 0; nt < 4; ++nt) {
        const bf16x4 xl = *(const bf16x4*)(bXl + swz(16 * nt + l15, 32 * wv + 8 * q));
#pragma unroll
        for (int r2 = 0; r2 < 4; ++r2) xlf[nt][r2] = (float)xl[r2];
    }

    const int i0 = ih * 32;
    {   // rbf(i0) -> bA
        const float dx = pjx - sPos[i0];
        const float dy = pjy - sPos[64 + i0];
        const float dz = pjz - sPos[128 + i0];
        const float d = __builtin_amdgcn_sqrtf(dx * dx + dy * dy + dz * dz);
        bf16x8 h0, h1v;
#pragma unroll
        for (int e = 0; e < 8; ++e) {
            float x0 = d - cc[e];
            float x1 = d - cc[8 + e];
            h0[e]  = (__bf16)fexp2(-14.4269504f * x0 * x0);
            h1v[e] = (__bf16)fexp2(-14.4269504f * x1 * x1);
        }
        *(bf16x8*)(bA + swz(lane, 32 * wv)) = h0;
        *(bf16x8*)(bA + swz(lane, 32 * wv + 16)) = h1v;
    }
    __syncthreads();

    for (int ii = 0; ii < 32; ++ii) {
        const int i = i0 + ii;
        // phase 1: h1 = tanh(Wf1 @ rbf + bf1) -> bB
        gemm64<1, false>(fWf1, bA, nullptr, bf1v, bB, lane, wv, nullptr);
        __syncthreads();
        // phase 2: h2 in-reg + cfconv -> gV[b][i]   ||   rbf(i+1) -> bA
        {
            f32x4 ret[4];
            gemm64<2, false>(fWf2, bB, nullptr, bf2v, nullptr, lane, wv, ret);
            float ts0 = 0.f, ts1 = 0.f, ts2 = 0.f, ts3 = 0.f;
#pragma unroll
            for (int nt = 0; nt < 4; ++nt) {
                const int j = 16 * nt + l15;
                const bool valid = (j != i);
                ts0 = fmaf(tanh_fast(ret[nt][0] + bf2v[0]), valid ? xlf[nt][0] : 0.f, ts0);
                ts1 = fmaf(tanh_fast(ret[nt][1] + bf2v[1]), valid ? xlf[nt][1] : 0.f, ts1);
                ts2 = fmaf(tanh_fast(ret[nt][2] + bf2v[2]), valid ? xlf[nt][2] : 0.f, ts2);
                ts3 = fmaf(tanh_fast(ret[nt][3] + bf2v[3]), valid ? xlf[nt][3] : 0.f, ts3);
            }
#pragma unroll
            for (int m = 1; m < 16; m <<= 1) {
                ts0 += __shfl_xor(ts0, m);
                ts1 += __shfl_xor(ts1, m);
                ts2 += __shfl_xor(ts2, m);
                ts3 += __shfl_xor(ts3, m);
            }
            if (l15 == 0) {
                bf16x4 o;
                o[0] = (__bf16)ts0; o[1] = (__bf16)ts1;
                o[2] = (__bf16)ts2; o[3] = (__bf16)ts3;
                *(bf16x4*)(gV + (b * 64 + i) * 64 + 16 * wv + 4 * q) = o;
            }
        }
        if (ii < 31) {
            const int inext = i + 1;
            const float dx = pjx - sPos[inext];
            const float dy = pjy - sPos[64 + inext];
            const float dz = pjz - sPos[128 + inext];
            const float d = __builtin_amdgcn_sqrtf(dx * dx + dy * dy + dz * dz);
            bf16x8 h0, h1v;
#pragma unroll
            for (int e = 0; e < 8; ++e) {
                float x0 = d - cc[e];
                float x1 = d - cc[8 + e];
                h0[e]  = (__bf16)fexp2(-14.4269504f * x0 * x0);
                h1v[e] = (__bf16)fexp2(-14.4269504f * x1 * x1);
            }
            *(bf16x8*)(bA + swz(lane, 32 * wv)) = h0;
            *(bf16x8*)(bA + swz(lane, 32 * wv + 16)) = h1v;
        }
        __syncthreads();
    }
}

// B: grid 512. v -> u -> X update (+ head at t==2). 33.4KB LDS.
__global__ __launch_bounds__(256, 2) void schnet_b(
    const float* __restrict__ bv1, const float* __restrict__ bv2,
    const float* __restrict__ b1,  const float* __restrict__ W2,
    const float* __restrict__ b2,  const char* __restrict__ wsW,
    float* __restrict__ gX, const __bf16* __restrict__ gV,
    float* __restrict__ out, int t) {
    extern __shared__ char smem[];
    char* bV   = smem;                      // 8192 v bf16
    char* bB   = smem + 8192;               // 8192 u bf16
    char* bX   = smem + 16384;              // 8192 X hi (head)
    char* bXlo = smem + 24576;              // 8192 X lo (head)
    float* sRed = (float*)(smem + 32768);   // [2][64]
    float* sW2v = (float*)(smem + 33280);   // 128B -> total 33408

    const int tid = threadIdx.x;
    const int lane = tid & 63, wv = tid >> 6;
    const int l15 = lane & 15, q = lane >> 4;
    const int b = blockIdx.x;

    if (tid < 32) sW2v[tid] = W2[tid];

    {   // stage v -> bV
        const int a = tid >> 2, f0 = (tid & 3) << 4;
        const __bf16* src = gV + (b * 64 + a) * 64 + f0;
        const bf16x8 v0 = *(const bf16x8*)(src);
        const bf16x8 v1 = *(const bf16x8*)(src + 8);
        *(bf16x8*)(bV + swz(a, 2 * f0)) = v0;
        *(bf16x8*)(bV + swz(a, 2 * f0 + 16)) = v1;
    }
    __syncthreads();
    {   // u = tanh(Wv1 @ v + bv1) -> bB
        const AFrag fWv1 = load_afrag(wsW, t * 5 + 3, wv, lane);
        const f32x4 bv1v = *(const f32x4*)(bv1 + t * 64 + 16 * wv + 4 * q);
        gemm64<1, false>(fWv1, bV, nullptr, bv1v, bB, lane, wv, nullptr);
    }
    __syncthreads();
    // X += Wv2 @ u + bv2 (global fp32 master)
    f32x4 master[4];
    {
        const AFrag fWv2 = load_afrag(wsW, t * 5 + 4, wv, lane);
        f32x4 ret[4];
        gemm64<2, false>(fWv2, bB, nullptr, f32x4{0.f, 0.f, 0.f, 0.f}, nullptr,
                         lane, wv, ret);
        const f32x4 bvec = *(const f32x4*)(bv2 + t * 64 + 16 * wv + 4 * q);
#pragma unroll
        for (int nt = 0; nt < 4; ++nt) {
            float* px = gX + b * 4096 + (16 * nt + l15) * 64 + 16 * wv + 4 * q;
            f32x4 m = *(const f32x4*)px;
#pragma unroll
            for (int rr = 0; rr < 4; ++rr) m[rr] += ret[nt][rr] + bvec[rr];
            *(f32x4*)px = m;
            master[nt] = m;
        }
    }

    if (t == 2) {
        // materialize X hi/lo planes for the head
#pragma unroll
        for (int nt = 0; nt < 4; ++nt) {
            bf16x4 oh, ol;
#pragma unroll
            for (int rr = 0; rr < 4; ++rr) {
                __bf16 h = (__bf16)master[nt][rr];
                oh[rr] = h;
                ol[rr] = (__bf16)(master[nt][rr] - (float)h);
            }
            const int off = swz(16 * nt + l15, 32 * wv + 8 * q);
            *(bf16x4*)(bX + off) = oh;
            *(bf16x4*)(bXlo + off) = ol;
        }
        __syncthreads();
        if (wv < 2) {
            const AFrag fW1 = load_afrag(wsW, 15, wv, lane);
            const f32x4 b1v = *(const f32x4*)(b1 + 16 * wv + 4 * q);
            const f32x4 w2v = *(const f32x4*)(sW2v + 16 * wv + 4 * q);
#pragma unroll
            for (int nt = 0; nt < 4; ++nt) {
                const int n = 16 * nt + l15;
                const bf16x8 b0h = *(const bf16x8*)(bX + swz(n, 16 * q));
                const bf16x8 b1h = *(const bf16x8*)(bX + swz(n, 64 + 16 * q));
                const bf16x8 b0l = *(const bf16x8*)(bXlo + swz(n, 16 * q));
                const bf16x8 b1l = *(const bf16x8*)(bXlo + swz(n, 64 + 16 * q));
                f32x4 c = {0.f, 0.f, 0.f, 0.f};
                c = __builtin_amdgcn_mfma_f32_16x16x32_bf16(fW1.a0h, b0h, c, 0, 0, 0);
                c = __builtin_amdgcn_mfma_f32_16x16x32_bf16(fW1.a1h, b1h, c, 0, 0, 0);
                c = __builtin_amdgcn_mfma_f32_16x16x32_bf16(fW1.a0h, b0l, c, 0, 0, 0);
                c = __builtin_amdgcn_mfma_f32_16x16x32_bf16(fW1.a1h, b1l, c, 0, 0, 0);
                c = __builtin_amdgcn_mfma_f32_16x16x32_bf16(fW1.a0l, b0h, c, 0, 0, 0);
                c = __builtin_amdgcn_mfma_f32_16x16x32_bf16(fW1.a1l, b1h, c, 0, 0, 0);
                float p = 0.f;
#pragma unroll
                for (int rr = 0; rr < 4; ++rr)
                    p = fmaf(tanh_fast(c[rr] + b1v[rr]), w2v[rr], p);
                p += __shfl_xor(p, 16);
                p += __shfl_xor(p, 32);
                if (q == 0) sRed[wv * 64 + nt * 16 + l15] = p;
            }
        }
        __syncthreads();
        if (tid < 64) {
            float s = sRed[tid] + sRed[64 + tid];
#pragma unroll
            for (int off = 1; off < 64; off <<= 1) s += __shfl_xor(s, off);
            if (tid == 0) out[b] = s + 64.0f * b2[0];
        }
    }
}

extern "C" void kernel_launch(void* const* d_in, const int* in_sizes, int n_in,
                              void* d_out, int out_size, void* d_ws, size_t ws_size,
                              hipStream_t stream) {
    const float* r    = (const float*)d_in[0];
    const float* v1   = (const float*)d_in[1];
    const float* v2   = (const float*)d_in[2];
    const float* cent = (const float*)d_in[3];
    const float* Wx   = (const float*)d_in[4];
    const float* bx   = (const float*)d_in[5];
    const float* Wf1  = (const float*)d_in[6];
    const float* bf1  = (const float*)d_in[7];
    const float* Wf2  = (const float*)d_in[8];
    const float* bf2  = (const float*)d_in[9];
    const float* Wv1  = (const float*)d_in[10];
    const float* bv1  = (const float*)d_in[11];
    const float* Wv2  = (const float*)d_in[12];
    const float* bv2  = (const float*)d_in[13];
    const float* W1   = (const float*)d_in[14];
    const float* b1   = (const float*)d_in[15];
    const float* W2   = (const float*)d_in[16];
    const float* b2   = (const float*)d_in[17];
    char* ws = (char*)d_ws;
    float*  gX = (float*)(ws + WS_X);
    __bf16* gV = (__bf16*)(ws + WS_V);

    prep_weights<<<16, 256, 0, stream>>>(Wx, Wf1, Wf2, Wv1, Wv2, W1, ws);
    init_x<<<512, 256, 0, stream>>>(v1, v2, gX);

    (void)hipFuncSetAttribute((const void*)schnet_a,
                              hipFuncAttributeMaxDynamicSharedMemorySize, 25600);
    (void)hipFuncSetAttribute((const void*)schnet_b,
                              hipFuncAttributeMaxDynamicSharedMemorySize, 33408);
    for (int t = 0; t < 3; ++t) {
        schnet_a<<<1024, 256, 25600, stream>>>(r, cent, bx, bf1, bf2, ws, gX, gV, t);
        schnet_b<<<512, 256, 33408, stream>>>(bv1, bv2, b1, W2, b2, ws, gX, gV,
                                              (float*)d_out, t);
    }
}